// Round 4
// baseline (566.919 us; speedup 1.0000x reference)
//
#include <hip/hip_runtime.h>
#include <cmath>

// ---------------------------------------------------------------------------
// Problem: out = x @ dequant(qweight, meta, scale)
//   x      : fp32 [M,K]; qweight: int32 [K,N] in [0,16)
//   meta   : int32 [K/4,N] in [0,6); scale: fp32 [K/128,N]; out: fp32 [M,N]
// R9 (visibility round): wall(553) - gemm(273) = ~280us unexplained vs ~55us
// component model; dequant never visible in top-5 (all slots = 270+us gemms).
// Changes: (1) gemm split into 2 half-M dispatches (~140us each) so any
// dispatch >150us becomes visible; (2) convert_x merged into dequant launch
// (one fewer graph node -> tests launch-overhead hypothesis); (3) dequant LDS
// transpose made conflict-free (nlane-spread rows + 16B-chunk XOR swizzle,
// replacing 8-way-conflicted stride-68 layout).
// ---------------------------------------------------------------------------

typedef __attribute__((ext_vector_type(8))) short bf16x8;
typedef __attribute__((ext_vector_type(4))) float f32x4;

__device__ inline unsigned short f2bf(float f) {
    union { float f; unsigned u; } v; v.f = f;
    unsigned r = (v.u + 0x7FFFu + ((v.u >> 16) & 1u)) >> 16;  // RNE
    return (unsigned short)r;
}

// ---------------------------------------------------------------------------
// Kernel 1: fused dequant+transpose AND x->bf16 convert.
//   blocks with by < gyD:  dequant one 64(k) x 64(n) tile.
//   blocks with by >= gyD: convert a 2048-element slice of x.
// Dequant mapping: nlane = t&15 (n within 16), kc = t>>4 (k-chunk of 4),
// rows r = nlane + 16*nn. q loads 64B-coalesced per 16-lane group.
// LDS [64 rows][64 ushorts], 8 bigchunks (16B) per row; thread's 8B piece at
// bigchunk (kc>>1)^(r&7), half kc&1 -> write banks <=2-way, read uniform.
// Pattern LUT nibbles: [1100]->3 [1010]->5 [1001]->9 [0110]->6 [0101]->A
// [0011]->C  => 0xCA6953
// ---------------------------------------------------------------------------
__global__ __launch_bounds__(256) void dequant_conv(
    const int* __restrict__ q, const int* __restrict__ meta,
    const float* __restrict__ scale,
    unsigned short* __restrict__ wt,   // [NC, K] chunk-local, bf16
    const float* __restrict__ x, unsigned short* __restrict__ xb,
    long long total, int gyD,
    int K, int N, int nbase)
{
    __shared__ __align__(16) unsigned short lds[64 * 64];
    const int t = threadIdx.x;

    if ((int)blockIdx.y >= gyD) {
        // ---- convert path: x fp32 -> bf16, 8 elem/thread, coalesced ----
        const long long cid = (long long)((int)blockIdx.y - gyD) * gridDim.x
                            + blockIdx.x;
        const long long base = (cid * 256 + t) * 8;
        if (base + 8 > total) return;
        const float4 a = *reinterpret_cast<const float4*>(x + base);
        const float4 b = *reinterpret_cast<const float4*>(x + base + 4);
        uint4 o;
        o.x = (unsigned)f2bf(a.x) | ((unsigned)f2bf(a.y) << 16);
        o.y = (unsigned)f2bf(a.z) | ((unsigned)f2bf(a.w) << 16);
        o.z = (unsigned)f2bf(b.x) | ((unsigned)f2bf(b.y) << 16);
        o.w = (unsigned)f2bf(b.z) | ((unsigned)f2bf(b.w) << 16);
        *reinterpret_cast<uint4*>(xb + base) = o;
        return;
    }

    // ---- dequant path ----
    const int nlane = t & 15;
    const int kc    = t >> 4;          // 0..15
    const int k0    = blockIdx.x * 64;
    const int nl0   = blockIdx.y * 64;
    const int g     = k0 >> 7;
    const int kbase = k0 + kc * 4;
    const unsigned lut = 0xCA6953u;

    #pragma unroll
    for (int nn = 0; nn < 4; ++nn) {
        const int r  = nlane + nn * 16;
        const int ng = nbase + nl0 + r;
        const float sc = scale[(size_t)g * N + ng];
        const int mv = meta[(size_t)(kbase >> 2) * N + ng];
        const unsigned pat = (lut >> (mv * 4)) & 0xFu;
        unsigned short w[4];
        #pragma unroll
        for (int j = 0; j < 4; ++j) {
            const int qv = q[(size_t)(kbase + j) * N + ng];
            const float wf = ((pat >> j) & 1u) ? (float)(qv - 8) * sc : 0.0f;
            w[j] = f2bf(wf);
        }
        uint2 pk;
        pk.x = (unsigned)w[0] | ((unsigned)w[1] << 16);
        pk.y = (unsigned)w[2] | ((unsigned)w[3] << 16);
        const int off = r * 64 + ((((kc >> 1) ^ (r & 7)) << 3) | ((kc & 1) << 2));
        *reinterpret_cast<uint2*>(&lds[off]) = pk;
    }
    __syncthreads();
    #pragma unroll
    for (int p = 0; p < 2; ++p) {
        const int idx = p * 256 + t;
        const int nr  = idx >> 3;
        const int ch  = idx & 7;
        const uint4 vv = *reinterpret_cast<const uint4*>(
            &lds[nr * 64 + ((ch ^ (nr & 7)) << 3)]);
        *reinterpret_cast<uint4*>(&wt[(size_t)(nl0 + nr) * K + k0 + ch * 8]) = vv;
    }
}

// ---------------------------------------------------------------------------
// Kernel 2: 256x256 8-phase GEMM over a half-M range.
// Structure unchanged from R8 (schedule proven insensitive): 8 waves 2Mx4N,
// BK=64, 128KiB LDS, chunk-XOR swizzle (0 conflicts), L2-rect grid mapping,
// counted vmcnt(6)@P3-close / vmcnt(4)@P4-close.
// ---------------------------------------------------------------------------
#define BAR() do { asm volatile("" ::: "memory"); \
                   __builtin_amdgcn_s_barrier(); \
                   asm volatile("" ::: "memory"); } while (0)

#define GLDS(g, s) __builtin_amdgcn_global_load_lds( \
    (const __attribute__((address_space(1))) void*)(g), \
    (__attribute__((address_space(3))) void*)(s), 16, 0, 0)

#define MFMA(d, x, y) d = __builtin_amdgcn_mfma_f32_16x16x32_bf16(x, y, d, 0, 0, 0)

__global__ __launch_bounds__(512, 2) void gemm256(
    const unsigned short* __restrict__ A,   // bf16 [M,K]
    const unsigned short* __restrict__ Bt,  // bf16 [NC,K] chunk-local
    float* __restrict__ C,                  // fp32 [M,N]
    int M, int N, int K, int nbase, int mbase)
{
    __shared__ __align__(16) unsigned short As[32768];
    __shared__ __align__(16) unsigned short Bs[32768];

    const int t    = threadIdx.x;
    const int w    = t >> 6;
    const int lane = t & 63;
    const int wm   = w >> 2;
    const int wn   = w & 3;
    const int l16  = lane & 15;
    const int quad = lane >> 4;

    // --- L2-rectangle grid mapping (R7-verified; adapts to per-launch grid) --
    const int gx = gridDim.x, gy = gridDim.y;
    int bid = blockIdx.y * gx + blockIdx.x;
    const int nwg = gx * gy;
    int m0, n0;
    if ((nwg & 7) == 0 && (gy & 1) == 0 && (gx & 3) == 0) {
        const int xcd = bid & 7;
        const int idx = bid >> 3;
        const int cpr = gx >> 2;
        const int lr  = idx / cpr;
        const int lc  = idx - lr * cpr;
        m0 = ((xcd >> 2) * (gy >> 1) + lr) * 256;
        n0 = ((xcd & 3) * cpr + lc) * 256;
    } else {
        int b2 = bid;
        if (nwg >= 8) {
            const int q8 = nwg >> 3, r8 = nwg & 7;
            const int xcd = bid & 7, off = bid >> 3;
            b2 = (xcd < r8 ? xcd * (q8 + 1) : r8 * (q8 + 1) + (xcd - r8) * q8) + off;
        }
        n0 = (b2 % gx) * 256;
        m0 = (b2 / gx) * 256;
    }
    m0 += mbase;

    const int    csrc = ((lane & 7) ^ ((lane >> 3) & 7)) * 8;
    const size_t aB = (size_t)(m0 + w * 8 + (lane >> 3)) * K + csrc;
    const size_t bB = (size_t)(n0 + w * 8 + (lane >> 3)) * K + csrc;
    const size_t J  = (size_t)64 * K;
    const size_t H  = (size_t)128 * K;
    const int sdst  = w * 512;

    const int sw0 = ((quad ^ (lane & 7)) * 8);
    const int sw1 = (((4 + quad) ^ (lane & 7)) * 8);
    const int aR  = wm * 8192 + l16 * 64;
    const int bR  = (wn >> 1) * 8192 + ((wn & 1) * 64 + l16) * 64;

    int kA = 0, kB = 0;

#define STAGE_A(buf, h) do { \
    GLDS(A + aB + (size_t)(h) * H + kA, &As[(buf)*16384 + (h)*8192 + sdst]); \
    GLDS(A + aB + (size_t)(h) * H + J + kA, &As[(buf)*16384 + (h)*8192 + 4096 + sdst]); \
  } while (0)
#define STAGE_B(buf, h) do { \
    GLDS(Bt + bB + (size_t)(h) * H + kB, &Bs[(buf)*16384 + (h)*8192 + sdst]); \
    GLDS(Bt + bB + (size_t)(h) * H + J + kB, &Bs[(buf)*16384 + (h)*8192 + 4096 + sdst]); \
  } while (0)

    f32x4 acc[8][4];
    #pragma unroll
    for (int i = 0; i < 8; ++i)
        #pragma unroll
        for (int j = 0; j < 4; ++j)
            acc[i][j] = (f32x4){0.f, 0.f, 0.f, 0.f};

    STAGE_A(0, 0); STAGE_A(0, 1); kA += 64;
    STAGE_B(0, 0); STAGE_B(0, 1); kB += 64;
    STAGE_B(1, 0); STAGE_B(1, 1); kB += 64;
    asm volatile("s_waitcnt vmcnt(4)" ::: "memory");
    BAR();

    bf16x8 a[4][2], bA_[2][2], bB_[2][2];

    #pragma unroll
    for (int j = 0; j < 2; ++j) {
        bA_[j][0] = *(const bf16x8*)&Bs[bR + j * 1024 + sw0];
        bA_[j][1] = *(const bf16x8*)&Bs[bR + j * 1024 + sw1];
    }

#define PHASES(buf, obuf, bcur, bnxt) do { \
  _Pragma("unroll") for (int i = 0; i < 4; ++i) { \
    a[i][0] = *(const bf16x8*)&As[(buf)*16384 + aR + i*1024 + sw0]; \
    a[i][1] = *(const bf16x8*)&As[(buf)*16384 + aR + i*1024 + sw1]; } \
  STAGE_A(obuf, 0); \
  BAR(); \
  asm volatile("s_waitcnt lgkmcnt(0)" ::: "memory"); \
  __builtin_amdgcn_s_setprio(1); \
  _Pragma("unroll") for (int i = 0; i < 4; ++i) \
    _Pragma("unroll") for (int j = 0; j < 2; ++j) { \
      MFMA(acc[i][j], a[i][0], bcur[j][0]); MFMA(acc[i][j], a[i][1], bcur[j][1]); } \
  __builtin_amdgcn_s_setprio(0); \
  BAR(); \
  _Pragma("unroll") for (int j = 0; j < 2; ++j) { \
    bnxt[j][0] = *(const bf16x8*)&Bs[(buf)*16384 + bR + (2+j)*1024 + sw0]; \
    bnxt[j][1] = *(const bf16x8*)&Bs[(buf)*16384 + bR + (2+j)*1024 + sw1]; } \
  STAGE_A(obuf, 1); kA += 64; if (kA >= K) kA = 0; \
  BAR(); \
  asm volatile("s_waitcnt lgkmcnt(0)" ::: "memory"); \
  __builtin_amdgcn_s_setprio(1); \
  _Pragma("unroll") for (int i = 0; i < 4; ++i) \
    _Pragma("unroll") for (int j = 0; j < 2; ++j) { \
      MFMA(acc[i][2+j], a[i][0], bnxt[j][0]); MFMA(acc[i][2+j], a[i][1], bnxt[j][1]); } \
  __builtin_amdgcn_s_setprio(0); \
  BAR(); \
  _Pragma("unroll") for (int i = 0; i < 4; ++i) { \
    a[i][0] = *(const bf16x8*)&As[(buf)*16384 + aR + (4+i)*1024 + sw0]; \
    a[i][1] = *(const bf16x8*)&As[(buf)*16384 + aR + (4+i)*1024 + sw1]; } \
  STAGE_B(buf, 0); \
  BAR(); \
  asm volatile("s_waitcnt lgkmcnt(0)" ::: "memory"); \
  __builtin_amdgcn_s_setprio(1); \
  _Pragma("unroll") for (int i = 0; i < 4; ++i) \
    _Pragma("unroll") for (int j = 0; j < 2; ++j) { \
      MFMA(acc[4+i][2+j], a[i][0], bnxt[j][0]); MFMA(acc[4+i][2+j], a[i][1], bnxt[j][1]); } \
  __builtin_amdgcn_s_setprio(0); \
  asm volatile("s_waitcnt vmcnt(6)" ::: "memory"); \
  BAR(); \
  _Pragma("unroll") for (int j = 0; j < 2; ++j) { \
    bnxt[j][0] = *(const bf16x8*)&Bs[(obuf)*16384 + bR + j*1024 + sw0]; \
    bnxt[j][1] = *(const bf16x8*)&Bs[(obuf)*16384 + bR + j*1024 + sw1]; } \
  STAGE_B(buf, 1); kB += 64; if (kB >= K) kB = 0; \
  BAR(); \
  asm volatile("s_waitcnt lgkmcnt(0)" ::: "memory"); \
  __builtin_amdgcn_s_setprio(1); \
  _Pragma("unroll") for (int i = 0; i < 4; ++i) \
    _Pragma("unroll") for (int j = 0; j < 2; ++j) { \
      MFMA(acc[4+i][j], a[i][0], bcur[j][0]); MFMA(acc[4+i][j], a[i][1], bcur[j][1]); } \
  __builtin_amdgcn_s_setprio(0); \
  asm volatile("s_waitcnt vmcnt(4)" ::: "memory"); \
  BAR(); \
} while (0)

    const int NIT = K >> 7;
    for (int it = 0; it < NIT; ++it) {
        PHASES(0, 1, bA_, bB_);
        PHASES(1, 0, bB_, bA_);
    }

    asm volatile("s_waitcnt vmcnt(0)" ::: "memory");

    const int mBase = m0 + wm * 128;
    const int nBase = nbase + n0 + wn * 64;
    #pragma unroll
    for (int i = 0; i < 8; ++i) {
        const int mrow = mBase + i * 16 + quad * 4;
        #pragma unroll
        for (int j = 0; j < 4; ++j) {
            const int ncol = nBase + j * 16 + l16;
            #pragma unroll
            for (int r = 0; r < 4; ++r)
                C[(size_t)(mrow + r) * N + ncol] = acc[i][j][r];
        }
    }
#undef STAGE_A
#undef STAGE_B
#undef PHASES
}

extern "C" void kernel_launch(void* const* d_in, const int* in_sizes, int n_in,
                              void* d_out, int out_size, void* d_ws, size_t ws_size,
                              hipStream_t stream)
{
    const float* x     = (const float*)d_in[0];   // fp32 [M,K]
    const int*   q     = (const int*)d_in[1];     // [K,N]
    const int*   meta  = (const int*)d_in[2];     // [K/4,N]
    const float* scale = (const float*)d_in[3];   // fp32 [K/128,N]
    float*       out   = (float*)d_out;           // fp32 [M,N]

    const double s0 = (double)in_sizes[0];
    const double s1 = (double)in_sizes[1];
    const int K = (int)llround(sqrt(s0 * s1 / (double)out_size));
    const int M = in_sizes[0] / K;
    const int N = in_sizes[1] / K;

    unsigned short* xb = (unsigned short*)d_ws;
    const size_t xb_bytes = (size_t)M * (size_t)K * 2;
    unsigned short* wt = (unsigned short*)((char*)d_ws + xb_bytes);
    const size_t wt_avail = ws_size > xb_bytes ? ws_size - xb_bytes : 0;

    const long long total = (long long)M * K;
    long long maxrows = (long long)(wt_avail / ((size_t)K * 2));
    int NC = (int)((maxrows / 256) * 256);   // gemm256 needs n-chunk % 256 == 0
    if (NC > N) NC = N;
    if (NC < 256) NC = 256;  // requires ws_size >= xb + 2 MiB

    const int gxD = K / 64;
    const long long conv_blocks = (total / 8 + 255) / 256;

    for (int nbase = 0; nbase < N; nbase += NC) {
        const int nc = (N - nbase) < NC ? (N - nbase) : NC;
        const int gyD = nc / 64;
        // convert rows only on first chunk
        const int gyC = (nbase == 0)
            ? (int)((conv_blocks + gxD - 1) / gxD) : 0;
        dim3 g1(gxD, gyD + gyC);
        dequant_conv<<<g1, dim3(256), 0, stream>>>(
            q, meta, scale, wt, x, xb, total, gyD, K, N, nbase);
        // gemm split into 2 half-M dispatches (visibility: each ~140us)
        const int Mh = M / 2;
        for (int h = 0; h < 2; ++h) {
            dim3 g2(nc / 256, Mh / 256);
            gemm256<<<g2, dim3(512), 0, stream>>>(
                xb, wt, out, M, N, K, nbase, h * Mh);
        }
    }
}